// Round 7
// baseline (7397.598 us; speedup 1.0000x reference)
//
#include <hip/hip_runtime.h>
#include <math.h>

typedef float v4 __attribute__((ext_vector_type(4)));
typedef unsigned long long u64;

static constexpr int B_ = 32;
static constexpr int S_ = 2048;
static constexpr int E_ = 512;
static constexpr int V_ = 32000;
static constexpr float EPS_ = 1e-6f;
static constexpr int NH_ = 8;     // blocks (column slices) per batch
static constexpr int CH_ = 64;    // columns per block

#define WG_ __HIP_MEMORY_SCOPE_WORKGROUP
#define AG_ __HIP_MEMORY_SCOPE_AGENT

// 16-row x 4-col matvec partial from an LDS row-vector (v4-aligned)
static __device__ __forceinline__ v4 mv16(const v4* w, const float* zp) {
    const v4 a = *(const v4*)(zp);
    const v4 b = *(const v4*)(zp + 4);
    const v4 c = *(const v4*)(zp + 8);
    const v4 d = *(const v4*)(zp + 12);
    v4 acc = a.x * w[0];
    acc += a.y * w[1];  acc += a.z * w[2];  acc += a.w * w[3];
    acc += b.x * w[4];  acc += b.y * w[5];  acc += b.z * w[6];  acc += b.w * w[7];
    acc += c.x * w[8];  acc += c.y * w[9];  acc += c.z * w[10]; acc += c.w * w[11];
    acc += d.x * w[12]; acc += d.y * w[13]; acc += d.z * w[14]; acc += d.w * w[15];
    return acc;
}
// reduce over the sub dimension (lanes cg, cg+16, cg+32, cg+48)
static __device__ __forceinline__ v4 red2(v4 acc) {
    acc.x += __shfl_down(acc.x, 16); acc.y += __shfl_down(acc.y, 16);
    acc.z += __shfl_down(acc.z, 16); acc.w += __shfl_down(acc.w, 16);
    acc.x += __shfl_down(acc.x, 32); acc.y += __shfl_down(acc.y, 32);
    acc.z += __shfl_down(acc.z, 32); acc.w += __shfl_down(acc.w, 32);
    return acc;
}

// ---------------------------------------------------------------------------
// K1: 8-blocks-per-batch scan, 256 blocks x 1024 threads (1 block/CU).
//
// ALGEBRAIC REFACTOR (removes LN from the serial chain). With A = I+W,
// u = LN(zmid)+x:  zmid' [c] = invd*(M_c - mu*G_c) + XB_c + bdec_c, where
//   M_c  = sum_r (gamma_r*zmid_r)*A[r][c]   (on RAW polled values; pollers
//                                            scale by gamma at LDS write)
//   G_c  = sum_r gamma_r*A[r][c]            (constant, precomputed once)
//   XB_c = sum_r (x_r+beta_r)*A[r][c]       (prefetched x -> computed
//                                            DURING the poll wait)
//   mu,invd: from per-slice (S,Q) published with values, consumed one full
//            step later (slack ~RT+500cy) by a dedicated stats wave.
// NO block-wide barriers in the loop: tagged LDS flag handshakes
// (vrdy/rdone/mtag/hseen/cnt) let waves de-skew instead of convoying.
// Exchange protocol: round-0 proven per-element TAGGED u64 relaxed agent
// atomics (tag travels with data, replay-safe via memset, 2-slot parity
// ring with full handshake -> no overwrite before global consumption).
// Waves: 0..7 compute (wave w owns rows 64w..64w+63; wave h also reduces,
// fixes, publishes), 8..14 value pollers (one foreign slice), 15 stats.
// ---------------------------------------------------------------------------
__global__ __launch_bounds__(1024) void scanfx(
    const int* __restrict__ seq,     // (B,S)
    const float* __restrict__ emb,   // (V,E)
    const float* __restrict__ Wdec,  // (E,E) row-major
    const float* __restrict__ bdec,  // (E)
    const float* __restrict__ gamma, // (E)
    const float* __restrict__ beta,  // (E)
    float* __restrict__ zout,        // (B,E)
    u64* __restrict__ zpub)          // values (B,2,E) + stats (B,2,2,8)
{
    __shared__ __align__(16) float zmG[2][E_];   // gamma*zmid, parity ring
    __shared__ __align__(16) float xbuf[2][E_];  // x+beta, parity ring
    __shared__ __align__(16) float part[NH_][CH_];
    __shared__ __align__(16) float xpart[NH_][CH_];
    __shared__ float munv[2][2];                 // (mu, invd) per parity
    __shared__ unsigned vrdy[2][NH_];            // slice-ready tags
    __shared__ unsigned rdone[NH_];              // slice read-release tags
    __shared__ unsigned mtag[2];                 // stats-ready tags
    __shared__ unsigned hseen;                   // wave-h stats consumption
    __shared__ unsigned cnt;                     // partials counter
    __shared__ int seq_l[S_];

    const int bid  = blockIdx.x;
    const int b    = bid & 31;
    const int h    = bid >> 5;
    const int c0   = h * CH_;
    const int tid  = threadIdx.x;
    const int wv   = tid >> 6;
    const int lane = tid & 63;
    const int cg   = lane & 15;
    const int sub  = lane >> 4;
    const bool comp = (wv < 8);
    const int row0 = wv * 64 + sub * 16;

    // --- A = W + I slice into VGPRs: rows row0..row0+15, cols c0+4cg..+3 ---
    v4 w[16];
    if (comp) {
        const float* wp = Wdec + (size_t)row0 * E_ + c0 + 4 * cg;
        #pragma unroll
        for (int q = 0; q < 16; ++q) {
            const float* p = wp + (size_t)q * E_;
            asm volatile("global_load_dwordx4 %0, %1, off\n\ts_waitcnt vmcnt(0)"
                         : "=v"(w[q]) : "v"(p));
        }
        const int cb = c0 + 4 * cg;
        #pragma unroll
        for (int q = 0; q < 16; ++q) {
            const int r = row0 + q;
            w[q].x += (r == cb + 0) ? 1.f : 0.f;
            w[q].y += (r == cb + 1) ? 1.f : 0.f;
            w[q].z += (r == cb + 2) ? 1.f : 0.f;
            w[q].w += (r == cb + 3) ? 1.f : 0.f;
        }
    }

    const int* seqb = seq + (size_t)b * S_;
    for (int i = tid; i < S_; i += 1024) seq_l[i] = seqb[i];

    const float sqrtE = sqrtf(512.0f);
    const float gmm = comp ? gamma[tid] : 0.f;
    const float btt = comp ? beta[tid]  : 0.f;
    const float bd  = (wv == h) ? bdec[c0 + lane]  : 0.f;
    const float gh  = (wv == h) ? gamma[c0 + lane] : 0.f;

    int fs = 0; float gf = 0.f;
    if (wv >= 8 && wv < 15) {
        const int j = wv - 8; fs = j + ((j >= h) ? 1 : 0);
        gf = gamma[fs * CH_ + lane];
    }

    u64* zpb = zpub + (size_t)b * 2 * E_;                     // values
    u64* zst = zpub + (size_t)B_ * 2 * E_ + (size_t)b * 32;   // stats

    if (comp) { zmG[1][tid] = gamma[tid]; zmG[0][tid] = 0.f; }
    if (tid < NH_) { vrdy[0][tid] = 0u; vrdy[1][tid] = 0u; rdone[tid] = 0u; }
    if (tid == 0) {
        mtag[0] = 0u; mtag[1] = 0u;
        munv[1][0] = 0.f; munv[1][1] = 0.f;   // t=0: mu=0, invd=0
        munv[0][0] = 0.f; munv[0][1] = 0.f;
        hseen = 0u; cnt = 0u;
    }
    __syncthreads();
    if (comp) xbuf[0][tid] = emb[(size_t)seq_l[0] * E_ + tid] * sqrtE; // t=0: no beta

    // --- G_c = sum_r gamma_r*A[r][c] (one pass; zmG[1] holds gamma) ---
    float Gc = 0.f;
    if (comp) {
        v4 g = red2(mv16(w, &zmG[1][row0]));
        if (lane < 16) *(v4*)&part[wv][4 * cg] = g;
    }
    __syncthreads();
    if (wv == h) {
        Gc = ((part[0][lane] + part[1][lane]) + (part[2][lane] + part[3][lane]))
           + ((part[4][lane] + part[5][lane]) + (part[6][lane] + part[7][lane]));
    }
    __syncthreads();

    for (int t = 0; t < S_; ++t) {
        const int pt = t & 1, pp = pt ^ 1;
        const unsigned tag = (unsigned)(t + 1);

        if (comp) {
            // prefetch next x (consumed at step end, hidden latency)
            const int tok = seq_l[(t + 1 < S_) ? t + 1 : t];
            const float ev = emb[(size_t)tok * E_ + tid];

            // XB partial: off-chain, runs during the poll wait
            v4 xacc = mv16(w, &xbuf[pt][row0]);

            // wait own slice of zmid_{t-1}
            while (__hip_atomic_load(&vrdy[pp][wv], __ATOMIC_ACQUIRE, WG_)
                   != (unsigned)t) __builtin_amdgcn_s_sleep(1);
            v4 macc = mv16(w, &zmG[pp][row0]);
            if (lane == 0)   // release buffer pp slice wv (reads complete)
                __hip_atomic_store(&rdone[wv], tag, __ATOMIC_RELEASE, WG_);

            macc = red2(macc); xacc = red2(xacc);
            if (lane < 16) {
                *(v4*)&part[wv][4 * cg]  = macc;
                *(v4*)&xpart[wv][4 * cg] = xacc;
            }
            if (lane == 0)
                __hip_atomic_fetch_add(&cnt, 1u, __ATOMIC_RELEASE, WG_);

            xbuf[pt ^ 1][tid] = fmaf(ev, sqrtE, btt);   // x_{t+1}+beta

            if (wv == h) {
                while (__hip_atomic_load(&cnt, __ATOMIC_ACQUIRE, WG_)
                       < 8u * tag) {}
                const float Mr =
                    ((part[0][lane] + part[1][lane]) + (part[2][lane] + part[3][lane]))
                  + ((part[4][lane] + part[5][lane]) + (part[6][lane] + part[7][lane]));
                const float Xr =
                    ((xpart[0][lane] + xpart[1][lane]) + (xpart[2][lane] + xpart[3][lane]))
                  + ((xpart[4][lane] + xpart[5][lane]) + (xpart[6][lane] + xpart[7][lane]));
                while (__hip_atomic_load(&mtag[pp], __ATOMIC_ACQUIRE, WG_)
                       != (unsigned)t) __builtin_amdgcn_s_sleep(1);
                const float mu  = munv[pp][0];
                const float inv = munv[pp][1];
                __hip_atomic_store(&hseen, tag, __ATOMIC_RELEASE, WG_);

                const float zmid = inv * (Mr - mu * Gc) + Xr + bd;
                union { float f; unsigned u; } cv; cv.f = zmid;
                __hip_atomic_store(&zpb[pt * E_ + c0 + lane],
                                   ((u64)tag << 32) | cv.u,
                                   __ATOMIC_RELAXED, AG_);
                zmG[pt][c0 + lane] = zmid * gh;
                asm volatile("s_waitcnt lgkmcnt(0)" ::: "memory");
                if (lane == 0)
                    __hip_atomic_store(&vrdy[pt][h], tag, __ATOMIC_RELEASE, WG_);

                // slice stats (off-chain: consumed next step with ~RT slack)
                float s = zmid, q2 = zmid * zmid;
                #pragma unroll
                for (int m = 1; m < 64; m <<= 1) {
                    s  += __shfl_xor(s, m);
                    q2 += __shfl_xor(q2, m);
                }
                if (lane == 0) {
                    union { float f; unsigned u; } c1, c2; c1.f = s; c2.f = q2;
                    __hip_atomic_store(&zst[pt * 16 + 0 + h],
                                       ((u64)tag << 32) | c1.u, __ATOMIC_RELAXED, AG_);
                    __hip_atomic_store(&zst[pt * 16 + 8 + h],
                                       ((u64)tag << 32) | c2.u, __ATOMIC_RELAXED, AG_);
                }
            }
        } else if (wv < 15) {
            // --- value poller: slice fs, 2-deep pipelined tagged poll ---
            const u64* ap = &zpb[pt * E_ + fs * CH_ + lane];
            u64 s0 = __hip_atomic_load(ap, __ATOMIC_RELAXED, AG_);
            u64 s1 = __hip_atomic_load(ap, __ATOMIC_RELAXED, AG_);
            float val = 0.f;
            bool done = false;
            for (;;) {
                if (!done && (unsigned)(s0 >> 32) == tag) {
                    val = __uint_as_float((unsigned)s0); done = true;
                }
                if (__all(done)) break;
                s0 = __hip_atomic_load(ap, __ATOMIC_RELAXED, AG_);
                if (!done && (unsigned)(s1 >> 32) == tag) {
                    val = __uint_as_float((unsigned)s1); done = true;
                }
                if (__all(done)) break;
                s1 = __hip_atomic_load(ap, __ATOMIC_RELAXED, AG_);
            }
            // gate: local reader of this parity buffer finished its read
            while (__hip_atomic_load(&rdone[fs], __ATOMIC_ACQUIRE, WG_)
                   < (unsigned)t) __builtin_amdgcn_s_sleep(1);
            zmG[pt][fs * CH_ + lane] = val * gf;
            asm volatile("s_waitcnt lgkmcnt(0)" ::: "memory");
            if (lane == 0)
                __hip_atomic_store(&vrdy[pt][fs], tag, __ATOMIC_RELEASE, WG_);
        } else {
            // --- stats wave: poll 16 (S,Q) words, reduce, write munv ---
            const bool need = (lane < 16);
            const u64* ap = &zst[pt * 16 + lane];
            bool done = !need; float sv = 0.f;
            do {
                if (!done) {
                    const u64 v = __hip_atomic_load(ap, __ATOMIC_RELAXED, AG_);
                    if ((unsigned)(v >> 32) == tag) {
                        sv = __uint_as_float((unsigned)v); done = true;
                    }
                }
            } while (!__all(done));
            sv += __shfl_xor(sv, 1);
            sv += __shfl_xor(sv, 2);
            sv += __shfl_xor(sv, 4);
            const float St = sv;              // lane0: sum S_i (fixed order)
            const float Qt = __shfl(sv, 8);   // lane8 group: sum Q_i
            const float mu  = St * (1.0f / E_);
            const float var = (Qt - St * mu) * (1.0f / (E_ - 1));
            const float inv = 1.0f / (sqrtf(var) + EPS_);
            while (__hip_atomic_load(&hseen, __ATOMIC_ACQUIRE, WG_)
                   < (unsigned)t) __builtin_amdgcn_s_sleep(1);
            if (lane == 0) {
                munv[pt][0] = mu; munv[pt][1] = inv;
                asm volatile("s_waitcnt lgkmcnt(0)" ::: "memory");
                __hip_atomic_store(&mtag[pt], tag, __ATOMIC_RELEASE, WG_);
            }
        }
    }

    // --- epilogue: block h==0 writes z_out = LN(zmid_{S-1}) ---
    if (h == 0 && comp) {
        const int pf = (S_ - 1) & 1;
        const unsigned ftag = (unsigned)S_;
        while (__hip_atomic_load(&vrdy[pf][wv], __ATOMIC_ACQUIRE, WG_)
               != ftag) __builtin_amdgcn_s_sleep(1);
        while (__hip_atomic_load(&mtag[pf], __ATOMIC_ACQUIRE, WG_)
               != ftag) __builtin_amdgcn_s_sleep(1);
        const float mu  = munv[pf][0];
        const float inv = munv[pf][1];
        zout[(size_t)b * E_ + tid] = inv * (zmG[pf][tid] - mu * gmm) + btt;
    }
}

// ---------------------------------------------------------------------------
// K2: y = z @ W_voc + b_voc. 250 blocks x 512 threads; each thread owns one
// vocab column for 8 batches (bg group). z reads are thread-uniform ->
// scalar-cache loads; W_voc streamed once (same cols across bg reuse L1).
// ---------------------------------------------------------------------------
__global__ __launch_bounds__(512) void logits_k(
    const float* __restrict__ zfin,  // (B,E)
    const float* __restrict__ Wvoc,  // (E,V)
    const float* __restrict__ bvoc,  // (V)
    float* __restrict__ y)           // (B,V)
{
    const int tid = threadIdx.x;
    const int col = blockIdx.x * 128 + (tid & 127);
    const int bg  = (tid >> 7) * 8;           // 0,8,16,24

    float acc[8] = {0.f, 0.f, 0.f, 0.f, 0.f, 0.f, 0.f, 0.f};
    const float* wp = Wvoc + col;
    const float* zp = zfin + (size_t)bg * E_;

    for (int k = 0; k < E_; k += 4) {
        const float w0 = wp[(size_t)(k + 0) * V_];
        const float w1 = wp[(size_t)(k + 1) * V_];
        const float w2 = wp[(size_t)(k + 2) * V_];
        const float w3 = wp[(size_t)(k + 3) * V_];
        #pragma unroll
        for (int g = 0; g < 8; ++g) {
            acc[g] = fmaf(zp[g * E_ + k + 0], w0, acc[g]);
            acc[g] = fmaf(zp[g * E_ + k + 1], w1, acc[g]);
            acc[g] = fmaf(zp[g * E_ + k + 2], w2, acc[g]);
            acc[g] = fmaf(zp[g * E_ + k + 3], w3, acc[g]);
        }
    }
    const float bv = bvoc[col];
    #pragma unroll
    for (int g = 0; g < 8; ++g)
        y[(size_t)(bg + g) * V_ + col] = acc[g] + bv;
}

// ---------------------------------------------------------------------------
// K3: per-batch log-sum-exp (bias already folded into y)
// ---------------------------------------------------------------------------
__global__ __launch_bounds__(1024) void lse_k(
    const float* __restrict__ y, float* __restrict__ corr)
{
    __shared__ float redm[16], redl[16];
    const int b = blockIdx.x;
    const int tid = threadIdx.x;
    const float* row = y + (size_t)b * V_;

    float m = -3.0e38f, l = 0.f;
    for (int v = tid; v < V_; v += 1024) {
        const float x = row[v];
        const float nm = fmaxf(m, x);
        l = l * __expf(m - nm) + __expf(x - nm);
        m = nm;
    }
    #pragma unroll
    for (int off = 32; off > 0; off >>= 1) {
        const float om = __shfl_down(m, off);
        const float ol = __shfl_down(l, off);
        const float nm = fmaxf(m, om);
        l = l * __expf(m - nm) + ol * __expf(om - nm);
        m = nm;
    }
    const int lane = tid & 63, wvv = tid >> 6;
    if (lane == 0) { redm[wvv] = m; redl[wvv] = l; }
    __syncthreads();
    if (tid == 0) {
        float M = redm[0], L = redl[0];
        for (int k = 1; k < 16; ++k) {
            const float nm = fmaxf(M, redm[k]);
            L = L * __expf(M - nm) + redl[k] * __expf(redm[k] - nm);
            M = nm;
        }
        corr[b] = M + logf(L);
    }
}

// ---------------------------------------------------------------------------
// K4: y -= corr[b]
// ---------------------------------------------------------------------------
__global__ __launch_bounds__(256) void fix_k(
    float* __restrict__ y, const float* __restrict__ corr)
{
    const int idx = blockIdx.x * 256 + threadIdx.x;   // float4 index
    const size_t o = (size_t)idx * 4;
    const int b = (int)(o / V_);
    const float cr = corr[b];
    v4 v = *(v4*)(y + o);
    v = v - cr;
    *(v4*)(y + o) = v;
}

// ---------------------------------------------------------------------------
extern "C" void kernel_launch(void* const* d_in, const int* in_sizes, int n_in,
                              void* d_out, int out_size, void* d_ws, size_t ws_size,
                              hipStream_t stream)
{
    (void)in_sizes; (void)n_in; (void)out_size; (void)ws_size;
    // 0=hidden_state (unused), 1=output_sequence, 2=emb_out, 3=W_dec,
    // 4=b_dec, 5=gamma, 6=beta, 7=W_voc, 8=b_voc
    const int*   seq  = (const int*)  d_in[1];
    const float* emb  = (const float*)d_in[2];
    const float* Wdec = (const float*)d_in[3];
    const float* bdec = (const float*)d_in[4];
    const float* gam  = (const float*)d_in[5];
    const float* bet  = (const float*)d_in[6];
    const float* Wvoc = (const float*)d_in[7];
    const float* bvoc = (const float*)d_in[8];

    float* out  = (float*)d_out;
    float* zout = out;            // B*E floats
    float* y    = out + B_ * E_;  // B*V floats

    // workspace: values (B*2*E u64) + stats (B*2*2*8 u64) + corr
    const size_t exch_u64 = (size_t)B_ * 2 * E_ + (size_t)B_ * 32;
    u64*   zpub = (u64*)d_ws;
    float* corr = (float*)((char*)d_ws + exch_u64 * sizeof(u64)); // B floats

    // tags must not alias t+1 from a previous replay — zero the exchange buf
    hipMemsetAsync(zpub, 0, exch_u64 * sizeof(u64), stream);

    hipLaunchKernelGGL(scanfx, dim3(B_ * NH_), dim3(1024), 0, stream,
                       seq, emb, Wdec, bdec, gam, bet, zout, zpub);
    hipLaunchKernelGGL(logits_k, dim3(V_ / 128), dim3(512), 0, stream,
                       zout, Wvoc, bvoc, y);
    hipLaunchKernelGGL(lse_k, dim3(B_), dim3(1024), 0, stream, y, corr);
    hipLaunchKernelGGL(fix_k, dim3(1000), dim3(256), 0, stream, y, corr);
}

// Round 9
// 3612.077 us; speedup vs baseline: 2.0480x; 2.0480x over previous
//
#include <hip/hip_runtime.h>
#include <math.h>

typedef float v4 __attribute__((ext_vector_type(4)));
typedef unsigned long long u64;

static constexpr int B_ = 32;
static constexpr int S_ = 2048;
static constexpr int E_ = 512;
static constexpr int V_ = 32000;
static constexpr float EPS_ = 1e-6f;
static constexpr int NH_ = 8;     // blocks (column slices) per batch
static constexpr int CH_ = 64;    // columns per block

#define AG_ __HIP_MEMORY_SCOPE_AGENT

// 16-row x 4-col matvec partial from an LDS row-vector (v4-aligned)
static __device__ __forceinline__ v4 mv16(const v4* w, const float* zp) {
    const v4 a = *(const v4*)(zp);
    const v4 b = *(const v4*)(zp + 4);
    const v4 c = *(const v4*)(zp + 8);
    const v4 d = *(const v4*)(zp + 12);
    v4 acc = a.x * w[0];
    acc += a.y * w[1];  acc += a.z * w[2];  acc += a.w * w[3];
    acc += b.x * w[4];  acc += b.y * w[5];  acc += b.z * w[6];  acc += b.w * w[7];
    acc += c.x * w[8];  acc += c.y * w[9];  acc += c.z * w[10]; acc += c.w * w[11];
    acc += d.x * w[12]; acc += d.y * w[13]; acc += d.z * w[14]; acc += d.w * w[15];
    return acc;
}
// reduce over the sub dimension (lanes cg, cg+16, cg+32, cg+48)
static __device__ __forceinline__ v4 red2(v4 acc) {
    acc.x += __shfl_down(acc.x, 16); acc.y += __shfl_down(acc.y, 16);
    acc.z += __shfl_down(acc.z, 16); acc.w += __shfl_down(acc.w, 16);
    acc.x += __shfl_down(acc.x, 32); acc.y += __shfl_down(acc.y, 32);
    acc.z += __shfl_down(acc.z, 32); acc.w += __shfl_down(acc.w, 32);
    return acc;
}

// ---------------------------------------------------------------------------
// K1: 8-blocks-per-batch scan, 256 blocks x 1024 threads (1 block/CU).
// Round-6 sync skeleton (2 __syncthreads/step, relaxed tagged u64 exchange,
// 7 dedicated poller waves) + algebraic LN removal:
//   zmid'[c] = inv*(M_c - mu*G_c) + XB_c + bdec_c,  A = I+W, where
//   M_c  = sum_r (gamma_r*zmid_r)*A[r][c]  -- matvec directly on the gathered
//          gamma-scaled buffer zmG (pollers scale at LDS write): the post-B2
//          serial segment (stats+LN+zs-write, ~550cy in R6) vanishes.
//   G_c  = sum_r gamma_r*A[r][c]           -- constant, precomputed.
//   XB_c = sum_r (x_k+beta)_r*A[r][c]      -- computed POST-B1 in the RT
//          shadow (x prefetched 2 steps ahead so emb-load never gates B1).
//   mu,inv (stats of zmid_{k-1}): wave 15 computes from raw copy zraw at the
//          TOP of iteration k (pre-B1, parallel with matvec, barrier-ordered
//          into wave 0's fix -- no flags, no exchange, no gating).
// Waves: 0..7 compute (wv 0 also reduces/fixes/publishes), 8..14 pollers,
// 15 stats. Barriers: B1 (partials ready), B2 (gather complete). Deadlock-
// free: publish depends only on B1 (local); polls are post-B1; distance-2
// parity ring; exact-match tags; replay-safe via memset.
// ---------------------------------------------------------------------------
__global__ __launch_bounds__(1024) void scanag(
    const int* __restrict__ seq,     // (B,S)
    const float* __restrict__ emb,   // (V,E)
    const float* __restrict__ Wdec,  // (E,E) row-major
    const float* __restrict__ bdec,  // (E)
    const float* __restrict__ gamma, // (E)
    const float* __restrict__ beta,  // (E)
    float* __restrict__ zout,        // (B,E)
    u64* __restrict__ zpub)          // values (B,2,E) tagged exchange
{
    __shared__ __align__(16) float zmG[E_];        // gamma*zmid (matvec src)
    __shared__ __align__(16) float zraw[E_];       // raw zmid (stats src)
    __shared__ __align__(16) float xbuf[2][E_];    // x+beta, parity
    __shared__ __align__(16) float part[NH_][CH_]; // M partials
    __shared__ __align__(16) float xpart[2][NH_][CH_]; // XB partials, parity
    __shared__ float munv[2][2];                   // (mu,inv), parity
    __shared__ int   seq_l[S_];

    const int bid  = blockIdx.x;
    const int b    = bid & 31;
    const int h    = bid >> 5;
    const int c0   = h * CH_;
    const int tid  = threadIdx.x;
    const int wv   = tid >> 6;
    const int lane = tid & 63;
    const int cg   = lane & 15;
    const int sub  = lane >> 4;
    const bool comp = (wv < 8);
    const int row0 = wv * 64 + sub * 16;

    // --- A = I+W slice: rows [row0,row0+16), cols c0+4cg..+3 (asm-pinned) ---
    v4 w[16];
    if (comp) {
        const float* wp = Wdec + (size_t)row0 * E_ + c0 + 4 * cg;
        #pragma unroll
        for (int q = 0; q < 16; ++q) {
            const float* p = wp + (size_t)q * E_;
            asm volatile("global_load_dwordx4 %0, %1, off\n\ts_waitcnt vmcnt(0)"
                         : "=v"(w[q]) : "v"(p));
        }
        const int cb = c0 + 4 * cg;
        #pragma unroll
        for (int q = 0; q < 16; ++q) {
            const int r = row0 + q;
            w[q].x += (r == cb + 0) ? 1.f : 0.f;
            w[q].y += (r == cb + 1) ? 1.f : 0.f;
            w[q].z += (r == cb + 2) ? 1.f : 0.f;
            w[q].w += (r == cb + 3) ? 1.f : 0.f;
        }
    }

    const int* seqb = seq + (size_t)b * S_;
    for (int i = tid; i < S_; i += 1024) seq_l[i] = seqb[i];

    const float sqrtE = sqrtf(512.0f);
    const float gmm = comp ? gamma[tid] : 0.f;
    const float btt = comp ? beta[tid]  : 0.f;
    const float bd  = (wv == 0) ? bdec[c0 + lane]  : 0.f;
    const float gh  = (wv == 0) ? gamma[c0 + lane] : 0.f;

    int fs = 0; float gf = 0.f;
    if (wv >= 8 && wv < 15) {
        const int j = wv - 8; fs = j + ((j >= h) ? 1 : 0);
        gf = gamma[fs * CH_ + lane];
    }

    u64* zpb = zpub + (size_t)b * 2 * E_;

    __syncthreads();                    // seq_l ready
    if (comp) {
        zmG[tid]  = 0.f;
        zraw[tid] = gamma[tid];         // temporarily gamma, for G_c pass
        xbuf[0][tid] = emb[(size_t)seq_l[0] * E_ + tid] * sqrtE;       // x_0
        xbuf[1][tid] = fmaf(emb[(size_t)seq_l[1] * E_ + tid], sqrtE, btt);
    }
    if (tid < 4) munv[tid >> 1][tid & 1] = 0.f;
    __syncthreads();
    if (comp) {                          // G_c partials + XB^0 partials
        v4 g = red2(mv16(w, &zraw[row0]));
        if (lane < 16) *(v4*)&part[wv][4 * cg] = g;
        v4 xa = red2(mv16(w, &xbuf[0][row0]));
        if (lane < 16) *(v4*)&xpart[0][wv][4 * cg] = xa;
    }
    __syncthreads();
    float Gc = 0.f;
    if (wv == 0)
        Gc = ((part[0][lane] + part[1][lane]) + (part[2][lane] + part[3][lane]))
           + ((part[4][lane] + part[5][lane]) + (part[6][lane] + part[7][lane]));
    __syncthreads();
    if (comp) zraw[tid] = 0.f;           // real role: raw zmid
    __syncthreads();

    for (int k = 0; k < S_; ++k) {
        const int pk = k & 1, pkn = pk ^ 1;
        const unsigned tag = (unsigned)(k + 1);

        float ev = 0.f;
        if (comp) {
            // prefetch x_{k+2} (consumed post-B1 -> never gates B1)
            const int kk = (k + 2 < S_) ? k + 2 : S_ - 1;
            ev = emb[(size_t)seq_l[kk] * E_ + tid];

            // --- M matvec on zmG (= gamma*zmid_{k-1}) ---
            v4 macc = red2(mv16(w, &zmG[row0]));
            if (lane < 16) *(v4*)&part[wv][4 * cg] = macc;
        } else if (wv == 15) {
            // --- stats of zmid_{k-1} from zraw (parallel with matvec) ---
            if (k) {
                float s = 0.f, q2 = 0.f;
                #pragma unroll
                for (int j = 0; j < 8; ++j) {
                    const float v = zraw[lane + 64 * j];
                    s += v; q2 += v * v;
                }
                #pragma unroll
                for (int m = 1; m < 64; m <<= 1) {
                    s  += __shfl_xor(s, m);
                    q2 += __shfl_xor(q2, m);
                }
                if (lane == 0) {
                    const float mu  = s * (1.0f / E_);
                    const float var = (q2 - s * mu) * (1.0f / (E_ - 1));
                    munv[pk][0] = mu;
                    munv[pk][1] = 1.0f / (sqrtf(var) + EPS_);
                }
            }
        }
        __syncthreads();                                   // B1

        if (wv == 0) {
            // --- col-reduce, fix, publish (the serial chain head) ---
            const float Mr =
                ((part[0][lane] + part[1][lane]) + (part[2][lane] + part[3][lane]))
              + ((part[4][lane] + part[5][lane]) + (part[6][lane] + part[7][lane]));
            const float Xr =
                ((xpart[pk][0][lane] + xpart[pk][1][lane])
               + (xpart[pk][2][lane] + xpart[pk][3][lane]))
              + ((xpart[pk][4][lane] + xpart[pk][5][lane])
               + (xpart[pk][6][lane] + xpart[pk][7][lane]));
            const float mu  = munv[pk][0];
            const float inv = munv[pk][1];
            const float zmid = inv * (Mr - mu * Gc) + Xr + bd;
            union { float f; unsigned u; } cv; cv.f = zmid;
            __hip_atomic_store(&zpb[pkn * E_ + c0 + lane],
                               ((u64)tag << 32) | cv.u,
                               __ATOMIC_RELAXED, AG_);
            zmG[c0 + lane]  = gh * zmid;
            zraw[c0 + lane] = zmid;
            // off-chain (RT shadow): XB^{k+1} partial rows 0..63 + x store
            v4 xa = red2(mv16(w, &xbuf[pkn][row0]));
            if (lane < 16) *(v4*)&xpart[pkn][0][4 * cg] = xa;
            xbuf[pk][lane] = fmaf(ev, sqrtE, btt);
        } else if (comp) {
            // --- XB^{k+1} partials + x_{k+2} store (RT shadow) ---
            v4 xa = red2(mv16(w, &xbuf[pkn][row0]));
            if (lane < 16) *(v4*)&xpart[pkn][wv][4 * cg] = xa;
            xbuf[pk][tid] = fmaf(ev, sqrtE, btt);
        } else if (wv < 15) {
            // --- 2-deep pipelined tagged poll (proven R6 pattern) ---
            const u64* ap = &zpb[pkn * E_ + fs * CH_ + lane];
            u64 s0 = __hip_atomic_load(ap, __ATOMIC_RELAXED, AG_);
            u64 s1 = __hip_atomic_load(ap, __ATOMIC_RELAXED, AG_);
            float val = 0.f;
            bool done = false;
            for (;;) {
                if (!done && (unsigned)(s0 >> 32) == tag) {
                    val = __uint_as_float((unsigned)s0); done = true;
                }
                if (__all(done)) break;
                s0 = __hip_atomic_load(ap, __ATOMIC_RELAXED, AG_);
                if (!done && (unsigned)(s1 >> 32) == tag) {
                    val = __uint_as_float((unsigned)s1); done = true;
                }
                if (__all(done)) break;
                s1 = __hip_atomic_load(ap, __ATOMIC_RELAXED, AG_);
            }
            zmG[fs * CH_ + lane]  = gf * val;
            zraw[fs * CH_ + lane] = val;
        }
        __syncthreads();                                   // B2
    }

    // --- epilogue: block h==0 writes z_out = LN(zmid_{S-1}) ---
    if (h == 0 && comp) {
        float s = 0.f, q2 = 0.f;
        #pragma unroll
        for (int j = 0; j < 8; ++j) {
            const float v = zraw[lane + 64 * j];
            s += v; q2 += v * v;
        }
        #pragma unroll
        for (int m = 1; m < 64; m <<= 1) {
            s  += __shfl_xor(s, m);
            q2 += __shfl_xor(q2, m);
        }
        const float mu  = s * (1.0f / E_);
        const float var = (q2 - s * mu) * (1.0f / (E_ - 1));
        const float inv = 1.0f / (sqrtf(var) + EPS_);
        zout[(size_t)b * E_ + tid] = gmm * (zraw[tid] - mu) * inv + btt;
    }
}

// ---------------------------------------------------------------------------
// K2: y = z @ W_voc + b_voc. 250 blocks x 512 threads; each thread owns one
// vocab column for 8 batches (bg group). z reads are thread-uniform ->
// scalar-cache loads; W_voc streamed once (same cols across bg reuse L1).
// ---------------------------------------------------------------------------
__global__ __launch_bounds__(512) void logits_k(
    const float* __restrict__ zfin,  // (B,E)
    const float* __restrict__ Wvoc,  // (E,V)
    const float* __restrict__ bvoc,  // (V)
    float* __restrict__ y)           // (B,V)
{
    const int tid = threadIdx.x;
    const int col = blockIdx.x * 128 + (tid & 127);
    const int bg  = (tid >> 7) * 8;           // 0,8,16,24

    float acc[8] = {0.f, 0.f, 0.f, 0.f, 0.f, 0.f, 0.f, 0.f};
    const float* wp = Wvoc + col;
    const float* zp = zfin + (size_t)bg * E_;

    for (int k = 0; k < E_; k += 4) {
        const float w0 = wp[(size_t)(k + 0) * V_];
        const float w1 = wp[(size_t)(k + 1) * V_];
        const float w2 = wp[(size_t)(k + 2) * V_];
        const float w3 = wp[(size_t)(k + 3) * V_];
        #pragma unroll
        for (int g = 0; g < 8; ++g) {
            acc[g] = fmaf(zp[g * E_ + k + 0], w0, acc[g]);
            acc[g] = fmaf(zp[g * E_ + k + 1], w1, acc[g]);
            acc[g] = fmaf(zp[g * E_ + k + 2], w2, acc[g]);
            acc[g] = fmaf(zp[g * E_ + k + 3], w3, acc[g]);
        }
    }
    const float bv = bvoc[col];
    #pragma unroll
    for (int g = 0; g < 8; ++g)
        y[(size_t)(bg + g) * V_ + col] = acc[g] + bv;
}

// ---------------------------------------------------------------------------
// K3: per-batch log-sum-exp (bias already folded into y)
// ---------------------------------------------------------------------------
__global__ __launch_bounds__(1024) void lse_k(
    const float* __restrict__ y, float* __restrict__ corr)
{
    __shared__ float redm[16], redl[16];
    const int b = blockIdx.x;
    const int tid = threadIdx.x;
    const float* row = y + (size_t)b * V_;

    float m = -3.0e38f, l = 0.f;
    for (int v = tid; v < V_; v += 1024) {
        const float x = row[v];
        const float nm = fmaxf(m, x);
        l = l * __expf(m - nm) + __expf(x - nm);
        m = nm;
    }
    #pragma unroll
    for (int off = 32; off > 0; off >>= 1) {
        const float om = __shfl_down(m, off);
        const float ol = __shfl_down(l, off);
        const float nm = fmaxf(m, om);
        l = l * __expf(m - nm) + ol * __expf(om - nm);
        m = nm;
    }
    const int lane = tid & 63, wvv = tid >> 6;
    if (lane == 0) { redm[wvv] = m; redl[wvv] = l; }
    __syncthreads();
    if (tid == 0) {
        float M = redm[0], L = redl[0];
        for (int k = 1; k < 16; ++k) {
            const float nm = fmaxf(M, redm[k]);
            L = L * __expf(M - nm) + redl[k] * __expf(redm[k] - nm);
            M = nm;
        }
        corr[b] = M + logf(L);
    }
}

// ---------------------------------------------------------------------------
// K4: y -= corr[b]
// ---------------------------------------------------------------------------
__global__ __launch_bounds__(256) void fix_k(
    float* __restrict__ y, const float* __restrict__ corr)
{
    const int idx = blockIdx.x * 256 + threadIdx.x;   // float4 index
    const size_t o = (size_t)idx * 4;
    const int b = (int)(o / V_);
    const float cr = corr[b];
    v4 v = *(v4*)(y + o);
    v = v - cr;
    *(v4*)(y + o) = v;
}

// ---------------------------------------------------------------------------
extern "C" void kernel_launch(void* const* d_in, const int* in_sizes, int n_in,
                              void* d_out, int out_size, void* d_ws, size_t ws_size,
                              hipStream_t stream)
{
    (void)in_sizes; (void)n_in; (void)out_size; (void)ws_size;
    // 0=hidden_state (unused), 1=output_sequence, 2=emb_out, 3=W_dec,
    // 4=b_dec, 5=gamma, 6=beta, 7=W_voc, 8=b_voc
    const int*   seq  = (const int*)  d_in[1];
    const float* emb  = (const float*)d_in[2];
    const float* Wdec = (const float*)d_in[3];
    const float* bdec = (const float*)d_in[4];
    const float* gam  = (const float*)d_in[5];
    const float* bet  = (const float*)d_in[6];
    const float* Wvoc = (const float*)d_in[7];
    const float* bvoc = (const float*)d_in[8];

    float* out  = (float*)d_out;
    float* zout = out;            // B*E floats
    float* y    = out + B_ * E_;  // B*V floats

    // workspace: values (B*2*E u64) + corr
    const size_t exch_u64 = (size_t)B_ * 2 * E_;
    u64*   zpub = (u64*)d_ws;
    float* corr = (float*)((char*)d_ws + exch_u64 * sizeof(u64)); // B floats

    // tags must not alias a previous replay — zero the exchange buf
    hipMemsetAsync(zpub, 0, exch_u64 * sizeof(u64), stream);

    hipLaunchKernelGGL(scanag, dim3(B_ * NH_), dim3(1024), 0, stream,
                       seq, emb, Wdec, bdec, gam, bet, zout, zpub);
    hipLaunchKernelGGL(logits_k, dim3(V_ / 128), dim3(512), 0, stream,
                       zout, Wvoc, bvoc, y);
    hipLaunchKernelGGL(lse_k, dim3(B_), dim3(1024), 0, stream, y, corr);
    hipLaunchKernelGGL(fix_k, dim3(1000), dim3(256), 0, stream, y, corr);
}